// Round 13
// baseline (819.472 us; speedup 1.0000x reference)
//
#include <hip/hip_runtime.h>
#include <stdint.h>

typedef __attribute__((ext_vector_type(8))) short    bh8;   // 8 x bf16 (4 VGPR)
typedef __attribute__((ext_vector_type(4))) float    fx4;   // MFMA acc
typedef __attribute__((ext_vector_type(4))) float    f4v;
typedef unsigned short u16;
typedef __attribute__((ext_vector_type(4))) unsigned short u16x4;

#define DEV static __device__ __forceinline__

DEV u16 f2bf(float f) {                       // RNE fp32 -> bf16
  unsigned u = __float_as_uint(f);
  u += 0x7FFFu + ((u >> 16) & 1u);
  return (u16)(u >> 16);
}
DEV float bf2f(u16 s) { return __uint_as_float(((unsigned)s) << 16); }
DEV float softplus_f(float x) { return fmaxf(x, 0.f) + log1pf(expf(-fabsf(x))); }

DEV void gload_lds16(const u16* g, u16* l) {  // 16B/lane async global->LDS
  __builtin_amdgcn_global_load_lds(
      (const __attribute__((address_space(1))) unsigned int*)g,
      (__attribute__((address_space(3))) unsigned int*)l, 16, 0, 0);
}
// 128 rows x 64 cols tile (ld=2048) with a 256-thread block: 4 gloads,
// each covers 32 rows (4 waves x 8 rows).
DEV void stage4(const u16* s, u16* d) {
  gload_lds16(s, d);
  gload_lds16(s + 65536,  d + 2048);
  gload_lds16(s + 131072, d + 4096);
  gload_lds16(s + 196608, d + 6144);
}

// ---------------- merged fp32 -> bf16 convert (1 launch for all 5) --------
// dst is the contiguous ws region: qb | kb | Wqb | Wkb | Wvb (u16).
__global__ __launch_bounds__(256) void k_cvt_all(
    const float* __restrict__ q, const float* __restrict__ k,
    const float* __restrict__ wq, const float* __restrict__ wk,
    const float* __restrict__ wv, u16* __restrict__ dst) {
  const int N4 = 19922944;                    // total f4 groups
  int i = blockIdx.x * 256 + threadIdx.x;
  int stride = gridDim.x * 256;
  for (; i < N4; i += stride) {
    const float* src; int off;
    if (i < 8388608)        { src = q;  off = i; }
    else if (i < 16777216)  { src = k;  off = i - 8388608; }
    else if (i < 17825792)  { src = wq; off = i - 16777216; }
    else if (i < 18874368)  { src = wk; off = i - 17825792; }
    else                    { src = wv; off = i - 18874368; }
    f4v v = ((const f4v*)src)[off];
    u16x4 o;
    o.x = f2bf(v.x); o.y = f2bf(v.y); o.z = f2bf(v.z); o.w = f2bf(v.w);
    ((u16x4*)dst)[i] = o;
  }
}

// ====== 128x128 GEMM, BK=64, 256 thr, 64KiB LDS -> 2 BLOCKS/CU ======
// C[i,j] = sum_k A[i,k]*B[j,k]; M=16384, N=2048, K=2048 hardcoded.
// r13 premise (r10 probes + m114): components stack serially because 1
// block/CU idles the CU at every drain/barrier. 2 blocks/CU puts 2 waves on
// each SIMD from DIFFERENT blocks (unaligned barriers) -> cross-block overlap.
// LDS (u16): buf0.A=0 buf0.B=8192 | buf1.A=16384 buf1.B=24576 (64 KiB).
// 4 waves (2Mx2N), per-wave 64x64 out: 16 fx4 acc (64 AGPR) + 16 bh8 frags.
// ds_read XOR-swizzle idx ^= (row&7)<<3; staging = linear LDS dest +
// inverse-swizzled global source (rule #21, verified r3-r12, conflicts=0).

#define MM(a, b, c) __builtin_amdgcn_mfma_f32_16x16x32_bf16(a, b, c, 0, 0, 0)
#define LD(BASE, RR, KS) \
  (*(const bh8*)&lsg[(BASE) + (RR) * 64 + ((((KS) * 32) + ko8) ^ swz)])

#define DECLQ(Q)                                                          \
  fx4 acc##Q##00 = {}, acc##Q##01 = {}, acc##Q##10 = {}, acc##Q##11 = {}, \
      acc##Q##20 = {}, acc##Q##21 = {}, acc##Q##30 = {}, acc##Q##31 = {}

#define DECLFRAGS                                                         \
  bh8 a_00 = {}, a_01 = {}, a_10 = {}, a_11 = {},                         \
      a_20 = {}, a_21 = {}, a_30 = {}, a_31 = {};                         \
  bh8 b0_00 = {}, b0_01 = {}, b0_10 = {}, b0_11 = {};                     \
  bh8 b1_00 = {}, b1_01 = {}, b1_10 = {}, b1_11 = {};

#define LDA4(AB, KS)                                                     \
  a_0##KS = LD(AB, arow0,      KS); a_1##KS = LD(AB, arow0 + 16, KS);    \
  a_2##KS = LD(AB, arow0 + 32, KS); a_3##KS = LD(AB, arow0 + 48, KS);

// BN selects the nj-pair: BN=0 -> rows brow0,+16 ; BN=1 -> +32,+48
#define LDB4(BN, BB, KS)                                                 \
  b##BN##_0##KS = LD(BB, brow0 + (BN) * 32,      KS);                    \
  b##BN##_1##KS = LD(BB, brow0 + (BN) * 32 + 16, KS);

#define MFMA8(Q, BN, KS)                                                 \
  acc##Q##00 = MM(a_0##KS, b##BN##_0##KS, acc##Q##00);                   \
  acc##Q##01 = MM(a_0##KS, b##BN##_1##KS, acc##Q##01);                   \
  acc##Q##10 = MM(a_1##KS, b##BN##_0##KS, acc##Q##10);                   \
  acc##Q##11 = MM(a_1##KS, b##BN##_1##KS, acc##Q##11);                   \
  acc##Q##20 = MM(a_2##KS, b##BN##_0##KS, acc##Q##20);                   \
  acc##Q##21 = MM(a_2##KS, b##BN##_1##KS, acc##Q##21);                   \
  acc##Q##30 = MM(a_3##KS, b##BN##_0##KS, acc##Q##30);                   \
  acc##Q##31 = MM(a_3##KS, b##BN##_1##KS, acc##Q##31);

// one K-tile: compute buf{AB,BB}, stage other buf {DA,DB} <- {SA,SB}
#define KTILE(AB, BB, SA, SB, DA, DB) {      \
  stage4(SA, lsu + (DA));                    \
  stage4(SB, lsu + (DB));                    \
  LDA4(AB, 0) LDA4(AB, 1)                    \
  LDB4(0, BB, 0) LDB4(0, BB, 1)              \
  LDB4(1, BB, 0) LDB4(1, BB, 1)              \
  __builtin_amdgcn_s_setprio(1);             \
  MFMA8(0, 0, 0) MFMA8(0, 0, 1)              \
  MFMA8(1, 1, 0) MFMA8(1, 1, 1)              \
  __builtin_amdgcn_s_setprio(0);             \
  asm volatile("s_waitcnt vmcnt(0)");        \
  __builtin_amdgcn_s_barrier();              \
}

#define STE(AC, EL, JOFF) {                                                   \
  float v = AC.EL;                                                            \
  if (EPI >= 1) v = softplus_f(v);                                            \
  if (EPI == 2) { if (mask[gi0 + JOFF]) v = 0.f; }                            \
  C[(size_t)(gi0 + JOFF) * 2048 + gj] = f2bf(v);                              \
}
#define ST1(AC, MI, NJ) {                                                     \
  int gi0 = bm0 + wr * 64 + (MI) * 16 + (lane >> 4) * 4;                      \
  int gj  = bn0 + wc * 64 + (NJ) * 16 + l15;                                  \
  STE(AC, x, 0) STE(AC, y, 1) STE(AC, z, 2) STE(AC, w, 3)                     \
}
#define EPIQ(Q, NB)                                                           \
  ST1(acc##Q##00, 0, NB) ST1(acc##Q##01, 0, (NB) + 1)                         \
  ST1(acc##Q##10, 1, NB) ST1(acc##Q##11, 1, (NB) + 1)                         \
  ST1(acc##Q##20, 2, NB) ST1(acc##Q##21, 2, (NB) + 1)                         \
  ST1(acc##Q##30, 3, NB) ST1(acc##Q##31, 3, (NB) + 1)

template <int EPI>   // 0 plain, 1 softplus, 2 softplus + row-mask zero
__global__ __launch_bounds__(256, 2) void k_gemm128(
    const u16* __restrict__ A, const u16* __restrict__ B, u16* __restrict__ C,
    const int* __restrict__ mask) {
  extern __shared__ u16 lsg[];                 // 64 KiB dynamic
  int tid = threadIdx.x, lane = tid & 63, wid = tid >> 6;   // 4 waves
  // XCD chunk: xcd owns 16 M-tiles; bn fast (B = 8MB total, L3-resident).
  int xcd = blockIdx.x & 7, i = blockIdx.x >> 3;
  int bm0 = (xcd * 16 + (i >> 4)) << 7;        // 128 M-tiles
  int bn0 = (i & 15) << 7;                     // 16 N-tiles
  int wr = wid >> 1, wc = wid & 1;
  int l15 = lane & 15, ko8 = (lane >> 4) * 8;
  int swz = (l15 & 7) << 3;
  int arow0 = wr * 64 + l15, brow0 = wc * 64 + l15;
  int lr = lane >> 3, cg = (lane & 7) ^ lr;    // inverse-swizzled source granule
  const u16* srcA = A + (size_t)(bm0 + wid * 8 + lr) * 2048 + cg * 8;
  const u16* srcB = B + (size_t)(bn0 + wid * 8 + lr) * 2048 + cg * 8;
  u16* lsu = lsg + wid * 512;                  // wave-uniform stage dest base

  DECLQ(0); DECLQ(1);
  DECLFRAGS

  // prologue: buf0 <- tile 0
  stage4(srcA, lsu + 0);
  stage4(srcB, lsu + 8192);
  asm volatile("s_waitcnt vmcnt(0)");
  __builtin_amdgcn_s_barrier();

  for (int it = 0; it < 16; it++) {
    const u16* sA1 = srcA + (2 * it + 1) * 64;
    const u16* sB1 = srcB + (2 * it + 1) * 64;
    int t2 = (2 * it + 2) & 31;                // wrapped (last-iter dup, unread)
    const u16* sA2 = srcA + t2 * 64;
    const u16* sB2 = srcB + t2 * 64;
    // even tile: compute buf0, stage buf1 <- 2it+1
    KTILE(0,     8192,  sA1, sB1, 16384, 24576)
    // odd tile: compute buf1, stage buf0 <- 2it+2
    KTILE(16384, 24576, sA2, sB2, 0,     8192)
  }

  // epilogue: D row=(lane>>4)*4+reg, col=lane&15 (m89-verified)
  EPIQ(0, 0)
  EPIQ(1, 2)
}

// ------- split-K kv: part[bid][e*128+d] = sum_{k in slab} pk[k,d]*v[k,e] ----
// also computes s-partials (column sums of pk over the slab) from registers.
__global__ __launch_bounds__(256, 2) void k_kv2(const u16* __restrict__ pk,
                                                const u16* __restrict__ v,
                                                float* __restrict__ part,
                                                float* __restrict__ spart) {
  int nh = blockIdx.x >> 3, slab = blockIdx.x & 7;
  int n = nh >> 4, h = nh & 15;
  __shared__ u16 lsA[128 * 32];   // pk^T tile: [d][k]
  __shared__ u16 lsB[128 * 32];   // v^T tile:  [e][k]
  __shared__ float redS[32][128];
  int tid = threadIdx.x, lane = tid & 63, wid = tid >> 6;
  int wr = wid >> 1, wc = wid & 1;
  int kk = tid >> 3;              // 0..31 (k within 32-k slab)
  int dg = (tid & 7) * 16;        // 0..112 (16 cols per thread)
  size_t rowbase = ((size_t)(n * 4096 + slab * 512) + kk) * 2048 + h * 128 + dg;
  int r = lane & 15, ko = (lane >> 4) * 8;
  fx4 acc[4][4] = {};
  float sA[16];
#pragma unroll
  for (int i = 0; i < 16; i++) sA[i] = 0.f;
  for (int k0 = 0; k0 < 512; k0 += 32) {
    __syncthreads();
    bh8 a0 = *(const bh8*)(pk + rowbase + (size_t)k0 * 2048);
    bh8 a1 = *(const bh8*)(pk + rowbase + (size_t)k0 * 2048 + 8);
    bh8 b0 = *(const bh8*)(v + rowbase + (size_t)k0 * 2048);
    bh8 b1 = *(const bh8*)(v + rowbase + (size_t)k0 * 2048 + 8);
#pragma unroll
    for (int i = 0; i < 8; i++) {
      sA[i] += bf2f((u16)a0[i]);
      sA[8 + i] += bf2f((u16)a1[i]);
    }
#pragma unroll
    for (int i = 0; i < 8; i++) {
      lsA[(dg + i) * 32 + kk] = (u16)a0[i];
      lsA[(dg + 8 + i) * 32 + kk] = (u16)a1[i];
      lsB[(dg + i) * 32 + kk] = (u16)b0[i];
      lsB[(dg + 8 + i) * 32 + kk] = (u16)b1[i];
    }
    __syncthreads();
    bh8 af[4], bfr[4];
#pragma unroll
    for (int mi = 0; mi < 4; mi++)
      af[mi] = *(const bh8*)&lsA[(wr * 64 + mi * 16 + r) * 32 + ko];
#pragma unroll
    for (int ni = 0; ni < 4; ni++)
      bfr[ni] = *(const bh8*)&lsB[(wc * 64 + ni * 16 + r) * 32 + ko];
#pragma unroll
    for (int mi = 0; mi < 4; mi++)
#pragma unroll
      for (int ni = 0; ni < 4; ni++)
        acc[mi][ni] = __builtin_amdgcn_mfma_f32_16x16x32_bf16(af[mi], bfr[ni],
                                                              acc[mi][ni], 0, 0, 0);
  }
#pragma unroll
  for (int mi = 0; mi < 4; mi++)
#pragma unroll
    for (int ni = 0; ni < 4; ni++)
#pragma unroll
      for (int j = 0; j < 4; j++) {
        int d = wr * 64 + mi * 16 + (lane >> 4) * 4 + j;
        int e = wc * 64 + ni * 16 + (lane & 15);
        part[(size_t)blockIdx.x * 16384 + e * 128 + d] = acc[mi][ni][j];
      }
#pragma unroll
  for (int i = 0; i < 16; i++) redS[kk][dg + i] = sA[i];
  __syncthreads();
  if (tid < 128) {
    float s = 0.f;
#pragma unroll
    for (int p = 0; p < 32; p++) s += redS[p][tid];
    spart[blockIdx.x * 128 + tid] = s;
  }
}

// ------- reduce split-K partials -> kvT (bf16) and s (f32) -------
__global__ __launch_bounds__(256) void k_red(const float* __restrict__ part,
                                             const float* __restrict__ spart,
                                             u16* __restrict__ kvT,
                                             float* __restrict__ sb) {
  int nh = blockIdx.x, tid = threadIdx.x;
  for (int i = tid; i < 16384; i += 256) {
    float s = 0.f;
#pragma unroll
    for (int sl = 0; sl < 8; sl++) s += part[(size_t)(nh * 8 + sl) * 16384 + i];
    kvT[(size_t)nh * 16384 + i] = f2bf(s);
  }
  if (tid < 128) {
    float s = 0.f;
#pragma unroll
    for (int sl = 0; sl < 8; sl++) s += spart[(nh * 8 + sl) * 128 + tid];
    sb[nh * 128 + tid] = s;
  }
}

// ---------------- final: out = (pq @ kv) / (pq @ s), query-masked ----------
__global__ __launch_bounds__(256, 2) void k_att(
    const u16* __restrict__ pq, const u16* __restrict__ kvT,
    const float* __restrict__ s, const int* __restrict__ qmask,
    float* __restrict__ out) {
  int b = blockIdx.x;
  int lt = b & 31, h = (b >> 5) & 15, nb = b >> 9;
  int l0 = lt * 128;
  __shared__ u16 lsQ[128 * 128];
  __shared__ u16 lsKV[128 * 128];
  __shared__ float lsS[128];
  __shared__ float lsDen[128];
  int tid = threadIdx.x, lane = tid & 63, wid = tid >> 6;

  int row = tid >> 1, part = tid & 1;
  const u16* gq = pq + ((size_t)(nb * 4096 + l0 + row)) * 2048 + h * 128 + part * 64;
  const u16* gk = kvT + ((size_t)(nb * 16 + h) * 128 + row) * 128 + part * 64;
  int sw = (row & 7) << 3;
#pragma unroll
  for (int j = 0; j < 8; j++) {
    bh8 vq = *(const bh8*)(gq + j * 8);
    bh8 vk = *(const bh8*)(gk + j * 8);
    int ci = (part * 64 + j * 8) ^ sw;
    *(bh8*)&lsQ[row * 128 + ci] = vq;
    *(bh8*)&lsKV[row * 128 + ci] = vk;
  }
  if (tid < 128) lsS[tid] = s[(nb * 16 + h) * 128 + tid];
  __syncthreads();

  if (tid < 128) {
    int rr = tid, swr = (rr & 7) << 3;
    float dsum = 0.f;
    for (int dd = 0; dd < 128; dd++) {
      int d = (dd + rr) & 127;
      dsum += bf2f(lsQ[rr * 128 + (d ^ swr)]) * lsS[d];
    }
    lsDen[rr] = dsum;
  }
  __syncthreads();

  int wr = wid >> 1, wc = wid & 1;
  int r = lane & 15, ko = (lane >> 4) * 8;
  fx4 acc[4][4] = {};
#pragma unroll
  for (int ks = 0; ks < 4; ks++) {
    bh8 af[4], bfr[4];
#pragma unroll
    for (int mi = 0; mi < 4; mi++) {
      int rw = wr * 64 + mi * 16 + r;
      af[mi] = *(const bh8*)&lsQ[rw * 128 + ((ks * 32 + ko) ^ ((rw & 7) << 3))];
    }
#pragma unroll
    for (int ni = 0; ni < 4; ni++) {
      int rw = wc * 64 + ni * 16 + r;
      bfr[ni] = *(const bh8*)&lsKV[rw * 128 + ((ks * 32 + ko) ^ ((rw & 7) << 3))];
    }
#pragma unroll
    for (int mi = 0; mi < 4; mi++)
#pragma unroll
      for (int ni = 0; ni < 4; ni++)
        acc[mi][ni] = __builtin_amdgcn_mfma_f32_16x16x32_bf16(af[mi], bfr[ni],
                                                              acc[mi][ni], 0, 0, 0);
  }
#pragma unroll
  for (int mi = 0; mi < 4; mi++)
#pragma unroll
    for (int ni = 0; ni < 4; ni++)
#pragma unroll
      for (int j = 0; j < 4; j++) {
        int li = wr * 64 + mi * 16 + (lane >> 4) * 4 + j;
        int e = wc * 64 + ni * 16 + (lane & 15);
        int l = l0 + li;
        float v = qmask[nb * 4096 + l] ? 0.f : acc[mi][ni][j] / lsDen[li];
        out[((size_t)(nb * 4096 + l)) * 2048 + h * 128 + e] = v;
      }
}

// ---------------- launch ----------------
extern "C" void kernel_launch(void* const* d_in, const int* in_sizes, int n_in,
                              void* d_out, int out_size, void* d_ws, size_t ws_size,
                              hipStream_t stream) {
  const float* query = (const float*)d_in[0];
  const float* key   = (const float*)d_in[1];
  const float* Wq    = (const float*)d_in[2];
  const float* Wk    = (const float*)d_in[3];
  const float* Wv    = (const float*)d_in[4];
  const int* qmask   = (const int*)d_in[5];
  const int* kmask   = (const int*)d_in[6];
  float* out = (float*)d_out;
  char* ws = (char*)d_ws;

  u16* qb   = (u16*)(ws + 0);
  u16* kb   = (u16*)(ws + 67108864ull);
  u16* Wqb  = (u16*)(ws + 134217728ull);
  u16* Wkb  = (u16*)(ws + 142606336ull);
  u16* Wvb  = (u16*)(ws + 150994944ull);
  u16* pq   = (u16*)(ws + 159383552ull);
  u16* kvT  = (u16*)(ws + 226492416ull);
  float* sb = (float*)(ws + 228589568ull);
  float* kvpart = (float*)(ws + 0);            // aliases dead qb
  float* spart  = (float*)(ws + 33554432ull);
  u16* pk = (u16*)d_out;
  u16* vb = (u16*)d_out + 33554432ull;

  k_cvt_all<<<2048, 256, 0, stream>>>(query, key, Wq, Wk, Wv, qb);

  k_gemm128<1><<<2048, 256, 65536, stream>>>(qb, Wqb, pq, nullptr);
  k_gemm128<2><<<2048, 256, 65536, stream>>>(kb, Wkb, pk, kmask);
  k_gemm128<0><<<2048, 256, 65536, stream>>>(kb, Wvb, vb, nullptr);

  k_kv2<<<512, 256, 0, stream>>>(pk, vb, kvpart, spart);
  k_red<<<64, 256, 0, stream>>>(kvpart, spart, kvT, sb);
  k_att<<<2048, 256, 0, stream>>>(pq, kvT, sb, qmask, out);
}

// Round 14
// 806.999 us; speedup vs baseline: 1.0155x; 1.0155x over previous
//
#include <hip/hip_runtime.h>
#include <stdint.h>

typedef __attribute__((ext_vector_type(8))) short    bh8;   // 8 x bf16 (4 VGPR)
typedef __attribute__((ext_vector_type(4))) float    fx4;   // MFMA acc
typedef __attribute__((ext_vector_type(4))) float    f4v;
typedef unsigned short u16;
typedef __attribute__((ext_vector_type(4))) unsigned short u16x4;

#define DEV static __device__ __forceinline__

DEV u16 f2bf(float f) {                       // RNE fp32 -> bf16
  unsigned u = __float_as_uint(f);
  u += 0x7FFFu + ((u >> 16) & 1u);
  return (u16)(u >> 16);
}
DEV float bf2f(u16 s) { return __uint_as_float(((unsigned)s) << 16); }
DEV float softplus_f(float x) { return fmaxf(x, 0.f) + log1pf(expf(-fabsf(x))); }

DEV void gload_lds16(const u16* g, u16* l) {  // 16B/lane async global->LDS
  __builtin_amdgcn_global_load_lds(
      (const __attribute__((address_space(1))) unsigned int*)g,
      (__attribute__((address_space(3))) unsigned int*)l, 16, 0, 0);
}
DEV void stage2(const u16* s, u16* d) {       // one 128-row half-tile piece
  gload_lds16(s, d);
  gload_lds16(s + 131072, d + 4096);          // +64 rows (ld = 2048)
}

// ---------------- merged fp32 -> bf16 convert (1 launch for all 5) --------
__global__ __launch_bounds__(256) void k_cvt_all(
    const float* __restrict__ q, const float* __restrict__ k,
    const float* __restrict__ wq, const float* __restrict__ wk,
    const float* __restrict__ wv, u16* __restrict__ dst) {
  const int N4 = 19922944;                    // total f4 groups
  int i = blockIdx.x * 256 + threadIdx.x;
  int stride = gridDim.x * 256;
  for (; i < N4; i += stride) {
    const float* src; int off;
    if (i < 8388608)        { src = q;  off = i; }
    else if (i < 16777216)  { src = k;  off = i - 8388608; }
    else if (i < 17825792)  { src = wq; off = i - 16777216; }
    else if (i < 18874368)  { src = wk; off = i - 17825792; }
    else                    { src = wv; off = i - 18874368; }
    f4v v = ((const f4v*)src)[off];
    u16x4 o;
    o.x = f2bf(v.x); o.y = f2bf(v.y); o.z = f2bf(v.z); o.w = f2bf(v.w);
    ((u16x4*)dst)[i] = o;
  }
}

// ====== 256x256 GEMM, REGISTER-SET PIPELINE (reads || independent MFMAs) ===
// C[i,j] = sum_k A[i,k]*B[j,k]; M=16384, N=2048, K=2048 hardcoded.
// LDS (u16): buf0.A h0=0 h1=8192, buf0.B h0=16384 h1=24576; buf1 = +32768.
// Two 12-frag register sets ping-pong at K-slice (32-col) granularity:
//   region = bar -> [stage(s1 only)] -> 12 ds_read into set X -> 32 MFMA on
//   set X^1 (read LAST region). MFMA operands are OLDER than the new reads ->
//   compiler's in-order partial lgkmcnt lets MFMA overlap the LDS port.
// Hazards: lgkm0+vmcnt0 at s0-region ends (drain ops >=1 region old -> free)
// + region-start barrier => cross-wave read-retire-before-restage and
// stage-complete-before-read. Stage only in s1 (buffer re-staged one full
// region after its last reads). XOR-swizzle + inv-swizzled source (rule #21).

#define MM(a, b, c) __builtin_amdgcn_mfma_f32_16x16x32_bf16(a, b, c, 0, 0, 0)
#define LD(BASE, RR, KS) \
  (*(const bh8*)&lsg[(BASE) + (RR) * 64 + ((((KS) * 32) + ko8) ^ swz)])

#define DECLQ(Q)                                                          \
  fx4 acc##Q##00 = {}, acc##Q##01 = {}, acc##Q##10 = {}, acc##Q##11 = {}, \
      acc##Q##20 = {}, acc##Q##21 = {}, acc##Q##30 = {}, acc##Q##31 = {}

#define DECLSET(S)                                                        \
  bh8 aA##S##0 = {}, aA##S##1 = {}, aA##S##2 = {}, aA##S##3 = {},         \
      aB##S##0 = {}, aB##S##1 = {}, aB##S##2 = {}, aB##S##3 = {},         \
      b0##S##0 = {}, b0##S##1 = {}, b1##S##0 = {}, b1##S##1 = {};

// 12 ds_read_b128: fill set S with K-slice KS of the tile in buffer BUF
#define RD(S, BUF, KS)                                                       \
  aA##S##0 = LD((BUF),         arow0,      KS);                              \
  aA##S##1 = LD((BUF),         arow0 + 16, KS);                              \
  aA##S##2 = LD((BUF),         arow0 + 32, KS);                              \
  aA##S##3 = LD((BUF),         arow0 + 48, KS);                              \
  aB##S##0 = LD((BUF) + 8192,  arow0,      KS);                              \
  aB##S##1 = LD((BUF) + 8192,  arow0 + 16, KS);                              \
  aB##S##2 = LD((BUF) + 8192,  arow0 + 32, KS);                              \
  aB##S##3 = LD((BUF) + 8192,  arow0 + 48, KS);                              \
  b0##S##0 = LD((BUF) + 16384, brow0,      KS);                              \
  b0##S##1 = LD((BUF) + 16384, brow0 + 16, KS);                              \
  b1##S##0 = LD((BUF) + 24576, brow0,      KS);                              \
  b1##S##1 = LD((BUF) + 24576, brow0 + 16, KS);

#define MQ(S, AH, BH, Q)                                                     \
  acc##Q##00 = MM(a##AH##S##0, b##BH##S##0, acc##Q##00);                     \
  acc##Q##01 = MM(a##AH##S##0, b##BH##S##1, acc##Q##01);                     \
  acc##Q##10 = MM(a##AH##S##1, b##BH##S##0, acc##Q##10);                     \
  acc##Q##11 = MM(a##AH##S##1, b##BH##S##1, acc##Q##11);                     \
  acc##Q##20 = MM(a##AH##S##2, b##BH##S##0, acc##Q##20);                     \
  acc##Q##21 = MM(a##AH##S##2, b##BH##S##1, acc##Q##21);                     \
  acc##Q##30 = MM(a##AH##S##3, b##BH##S##0, acc##Q##30);                     \
  acc##Q##31 = MM(a##AH##S##3, b##BH##S##1, acc##Q##31);
#define MFMA32(S) MQ(S, A, 0, 0) MQ(S, A, 1, 1) MQ(S, B, 0, 2) MQ(S, B, 1, 3)

#define STAGE8(SA, SB, DBUF)                                                 \
  stage2((SA),          lsu + (DBUF));                                       \
  stage2((SA) + 262144, lsu + (DBUF) + 8192);                                \
  stage2((SB),          lsu + (DBUF) + 16384);                               \
  stage2((SB) + 262144, lsu + (DBUF) + 24576);

// s0-region: MFMA set RS (tile t slice 0), read set WS = tile t slice 1
#define REGION_S0(RS, WS, BUF) {                 \
  __builtin_amdgcn_s_barrier();                  \
  RD(WS, BUF, 1)                                 \
  __builtin_amdgcn_s_setprio(1);                 \
  MFMA32(RS)                                     \
  __builtin_amdgcn_s_setprio(0);                 \
  asm volatile("s_waitcnt lgkmcnt(0)");          \
  asm volatile("s_waitcnt vmcnt(0)");            \
}
// s1-region: stage tile t+2 -> BUF(t), read set WS = tile t+1 slice 0 from
// the OTHER buffer, MFMA set RS (tile t slice 1)
#define REGION_S1(RS, WS, BUF, SA, SB) {         \
  __builtin_amdgcn_s_barrier();                  \
  STAGE8(SA, SB, BUF)                            \
  RD(WS, (BUF) ^ 32768, 0)                       \
  __builtin_amdgcn_s_setprio(1);                 \
  MFMA32(RS)                                     \
  __builtin_amdgcn_s_setprio(0);                 \
}

#define STE(AC, EL, JOFF) {                                                   \
  float v = AC.EL;                                                            \
  if (EPI >= 1) v = softplus_f(v);                                            \
  if (EPI == 2) { if (mask[gi0 + JOFF]) v = 0.f; }                            \
  C[(size_t)(gi0 + JOFF) * 2048 + gj] = f2bf(v);                              \
}
#define ST1(AC, QR, QC, MI, NI) {                                             \
  int gi0 = bm0 + (QR) * 128 + wr * 64 + (MI) * 16 + (lane >> 4) * 4;         \
  int gj  = bn0 + (QC) * 128 + wc * 32 + (NI) * 16 + l15;                     \
  STE(AC, x, 0) STE(AC, y, 1) STE(AC, z, 2) STE(AC, w, 3)                     \
}
#define EPIQ(Q, QR, QC)                                                       \
  ST1(acc##Q##00, QR, QC, 0, 0) ST1(acc##Q##01, QR, QC, 0, 1)                 \
  ST1(acc##Q##10, QR, QC, 1, 0) ST1(acc##Q##11, QR, QC, 1, 1)                 \
  ST1(acc##Q##20, QR, QC, 2, 0) ST1(acc##Q##21, QR, QC, 2, 1)                 \
  ST1(acc##Q##30, QR, QC, 3, 0) ST1(acc##Q##31, QR, QC, 3, 1)

template <int EPI>   // 0 plain, 1 softplus, 2 softplus + row-mask zero
__global__ __launch_bounds__(512, 2) void k_gemm256(
    const u16* __restrict__ A, const u16* __restrict__ B, u16* __restrict__ C,
    const int* __restrict__ mask) {
  extern __shared__ u16 lsg[];                 // 128 KiB dynamic
  int tid = threadIdx.x, lane = tid & 63, wid = tid >> 6;
  int xcd = blockIdx.x & 7, i = blockIdx.x >> 3;
  int bm0 = (xcd * 8 + (i & 7)) << 8;          // 64 M-tiles, XCD-exclusive
  int bn0 = (i >> 3) << 8;                     // 8 N-tiles
  int wr = wid >> 2, wc = wid & 3;
  int l15 = lane & 15, ko8 = (lane >> 4) * 8;
  int swz = (l15 & 7) << 3;
  int arow0 = wr * 64 + l15, brow0 = wc * 32 + l15;
  int lr = lane >> 3, cg = (lane & 7) ^ lr;    // inverse-swizzled source granule
  const u16* srcA = A + (size_t)(bm0 + wid * 8 + lr) * 2048 + cg * 8;
  const u16* srcB = B + (size_t)(bn0 + wid * 8 + lr) * 2048 + cg * 8;
  u16* lsu = lsg + wid * 512;                  // wave-uniform stage dest base

  DECLQ(0); DECLQ(1); DECLQ(2); DECLQ(3);
  DECLSET(0) DECLSET(1)

  // prologue: buf0 <- t0, buf1 <- t1; drain t0; read t0 slice0 into set0.
  STAGE8(srcA, srcB, 0)
  STAGE8(srcA + 64, srcB + 64, 32768)
  asm volatile("s_waitcnt vmcnt(8)");
  __builtin_amdgcn_s_barrier();
  RD(0, 0, 0)

  for (int it = 0; it < 16; it++) {
    const u16* sA2 = srcA + ((2 * it + 2) & 31) * 64;
    const u16* sB2 = srcB + ((2 * it + 2) & 31) * 64;
    const u16* sA3 = srcA + ((2 * it + 3) & 31) * 64;
    const u16* sB3 = srcB + ((2 * it + 3) & 31) * 64;
    // tile 2it (buf0): set0 holds s0; read s1 into set1; then s1-region
    REGION_S0(0, 1, 0)
    REGION_S1(1, 0, 0, sA2, sB2)         // stage t+2->buf0, read t+1 s0 (buf1)
    // tile 2it+1 (buf1)
    REGION_S0(0, 1, 32768)
    REGION_S1(1, 0, 32768, sA3, sB3)     // stage t+3->buf1, read t+2 s0 (buf0)
  }

  // epilogue: D row=(lane>>4)*4+reg, col=lane&15 (m89-verified)
  EPIQ(0, 0, 0)
  EPIQ(1, 0, 1)
  EPIQ(2, 1, 0)
  EPIQ(3, 1, 1)
}

// ------- split-K kv: part[bid][e*128+d] = sum_{k in slab} pk[k,d]*v[k,e] ----
__global__ __launch_bounds__(256, 2) void k_kv2(const u16* __restrict__ pk,
                                                const u16* __restrict__ v,
                                                float* __restrict__ part,
                                                float* __restrict__ spart) {
  int nh = blockIdx.x >> 3, slab = blockIdx.x & 7;
  int n = nh >> 4, h = nh & 15;
  __shared__ u16 lsA[128 * 32];
  __shared__ u16 lsB[128 * 32];
  __shared__ float redS[32][128];
  int tid = threadIdx.x, lane = tid & 63, wid = tid >> 6;
  int wr = wid >> 1, wc = wid & 1;
  int kk = tid >> 3;
  int dg = (tid & 7) * 16;
  size_t rowbase = ((size_t)(n * 4096 + slab * 512) + kk) * 2048 + h * 128 + dg;
  int r = lane & 15, ko = (lane >> 4) * 8;
  fx4 acc[4][4] = {};
  float sA[16];
#pragma unroll
  for (int i = 0; i < 16; i++) sA[i] = 0.f;
  for (int k0 = 0; k0 < 512; k0 += 32) {
    __syncthreads();
    bh8 a0 = *(const bh8*)(pk + rowbase + (size_t)k0 * 2048);
    bh8 a1 = *(const bh8*)(pk + rowbase + (size_t)k0 * 2048 + 8);
    bh8 b0 = *(const bh8*)(v + rowbase + (size_t)k0 * 2048);
    bh8 b1 = *(const bh8*)(v + rowbase + (size_t)k0 * 2048 + 8);
#pragma unroll
    for (int i = 0; i < 8; i++) {
      sA[i] += bf2f((u16)a0[i]);
      sA[8 + i] += bf2f((u16)a1[i]);
    }
#pragma unroll
    for (int i = 0; i < 8; i++) {
      lsA[(dg + i) * 32 + kk] = (u16)a0[i];
      lsA[(dg + 8 + i) * 32 + kk] = (u16)a1[i];
      lsB[(dg + i) * 32 + kk] = (u16)b0[i];
      lsB[(dg + 8 + i) * 32 + kk] = (u16)b1[i];
    }
    __syncthreads();
    bh8 af[4], bfr[4];
#pragma unroll
    for (int mi = 0; mi < 4; mi++)
      af[mi] = *(const bh8*)&lsA[(wr * 64 + mi * 16 + r) * 32 + ko];
#pragma unroll
    for (int ni = 0; ni < 4; ni++)
      bfr[ni] = *(const bh8*)&lsB[(wc * 64 + ni * 16 + r) * 32 + ko];
#pragma unroll
    for (int mi = 0; mi < 4; mi++)
#pragma unroll
      for (int ni = 0; ni < 4; ni++)
        acc[mi][ni] = __builtin_amdgcn_mfma_f32_16x16x32_bf16(af[mi], bfr[ni],
                                                              acc[mi][ni], 0, 0, 0);
  }
#pragma unroll
  for (int mi = 0; mi < 4; mi++)
#pragma unroll
    for (int ni = 0; ni < 4; ni++)
#pragma unroll
      for (int j = 0; j < 4; j++) {
        int d = wr * 64 + mi * 16 + (lane >> 4) * 4 + j;
        int e = wc * 64 + ni * 16 + (lane & 15);
        part[(size_t)blockIdx.x * 16384 + e * 128 + d] = acc[mi][ni][j];
      }
#pragma unroll
  for (int i = 0; i < 16; i++) redS[kk][dg + i] = sA[i];
  __syncthreads();
  if (tid < 128) {
    float s = 0.f;
#pragma unroll
    for (int p = 0; p < 32; p++) s += redS[p][tid];
    spart[blockIdx.x * 128 + tid] = s;
  }
}

// ------- reduce split-K partials -> kvT (bf16) and s (f32) -------
__global__ __launch_bounds__(256) void k_red(const float* __restrict__ part,
                                             const float* __restrict__ spart,
                                             u16* __restrict__ kvT,
                                             float* __restrict__ sb) {
  int nh = blockIdx.x, tid = threadIdx.x;
  for (int i = tid; i < 16384; i += 256) {
    float s = 0.f;
#pragma unroll
    for (int sl = 0; sl < 8; sl++) s += part[(size_t)(nh * 8 + sl) * 16384 + i];
    kvT[(size_t)nh * 16384 + i] = f2bf(s);
  }
  if (tid < 128) {
    float s = 0.f;
#pragma unroll
    for (int sl = 0; sl < 8; sl++) s += spart[(nh * 8 + sl) * 128 + tid];
    sb[nh * 128 + tid] = s;
  }
}

// ---------------- final: out = (pq @ kv) / (pq @ s), query-masked ----------
__global__ __launch_bounds__(256, 2) void k_att(
    const u16* __restrict__ pq, const u16* __restrict__ kvT,
    const float* __restrict__ s, const int* __restrict__ qmask,
    float* __restrict__ out) {
  int b = blockIdx.x;
  int lt = b & 31, h = (b >> 5) & 15, nb = b >> 9;
  int l0 = lt * 128;
  __shared__ u16 lsQ[128 * 128];
  __shared__ u16 lsKV[128 * 128];
  __shared__ float lsS[128];
  __shared__ float lsDen[128];
  int tid = threadIdx.x, lane = tid & 63, wid = tid >> 6;

  int row = tid >> 1, part = tid & 1;
  const u16* gq = pq + ((size_t)(nb * 4096 + l0 + row)) * 2048 + h * 128 + part * 64;
  const u16* gk = kvT + ((size_t)(nb * 16 + h) * 128 + row) * 128 + part * 64;
  int sw = (row & 7) << 3;
#pragma unroll
  for (int j = 0; j < 8; j++) {
    bh8 vq = *(const bh8*)(gq + j * 8);
    bh8 vk = *(const bh8*)(gk + j * 8);
    int ci = (part * 64 + j * 8) ^ sw;
    *(bh8*)&lsQ[row * 128 + ci] = vq;
    *(bh8*)&lsKV[row * 128 + ci] = vk;
  }
  if (tid < 128) lsS[tid] = s[(nb * 16 + h) * 128 + tid];
  __syncthreads();

  if (tid < 128) {
    int rr = tid, swr = (rr & 7) << 3;
    float dsum = 0.f;
    for (int dd = 0; dd < 128; dd++) {
      int d = (dd + rr) & 127;
      dsum += bf2f(lsQ[rr * 128 + (d ^ swr)]) * lsS[d];
    }
    lsDen[rr] = dsum;
  }
  __syncthreads();

  int wr = wid >> 1, wc = wid & 1;
  int r = lane & 15, ko = (lane >> 4) * 8;
  fx4 acc[4][4] = {};
#pragma unroll
  for (int ks = 0; ks < 4; ks++) {
    bh8 af[4], bfr[4];
#pragma unroll
    for (int mi = 0; mi < 4; mi++) {
      int rw = wr * 64 + mi * 16 + r;
      af[mi] = *(const bh8*)&lsQ[rw * 128 + ((ks * 32 + ko) ^ ((rw & 7) << 3))];
    }
#pragma unroll
    for (int ni = 0; ni < 4; ni++) {
      int rw = wc * 64 + ni * 16 + r;
      bfr[ni] = *(const bh8*)&lsKV[rw * 128 + ((ks * 32 + ko) ^ ((rw & 7) << 3))];
    }
#pragma unroll
    for (int mi = 0; mi < 4; mi++)
#pragma unroll
      for (int ni = 0; ni < 4; ni++)
        acc[mi][ni] = __builtin_amdgcn_mfma_f32_16x16x32_bf16(af[mi], bfr[ni],
                                                              acc[mi][ni], 0, 0, 0);
  }
#pragma unroll
  for (int mi = 0; mi < 4; mi++)
#pragma unroll
    for (int ni = 0; ni < 4; ni++)
#pragma unroll
      for (int j = 0; j < 4; j++) {
        int li = wr * 64 + mi * 16 + (lane >> 4) * 4 + j;
        int e = wc * 64 + ni * 16 + (lane & 15);
        int l = l0 + li;
        float v = qmask[nb * 4096 + l] ? 0.f : acc[mi][ni][j] / lsDen[li];
        out[((size_t)(nb * 4096 + l)) * 2048 + h * 128 + e] = v;
      }
}

// ---------------- launch ----------------
extern "C" void kernel_launch(void* const* d_in, const int* in_sizes, int n_in,
                              void* d_out, int out_size, void* d_ws, size_t ws_size,
                              hipStream_t stream) {
  const float* query = (const float*)d_in[0];
  const float* key   = (const float*)d_in[1];
  const float* Wq    = (const float*)d_in[2];
  const float* Wk    = (const float*)d_in[3];
  const float* Wv    = (const float*)d_in[4];
  const int* qmask   = (const int*)d_in[5];
  const int* kmask   = (const int*)d_in[6];
  float* out = (float*)d_out;
  char* ws = (char*)d_ws;

  u16* qb   = (u16*)(ws + 0);
  u16* kb   = (u16*)(ws + 67108864ull);
  u16* Wqb  = (u16*)(ws + 134217728ull);
  u16* Wkb  = (u16*)(ws + 142606336ull);
  u16* Wvb  = (u16*)(ws + 150994944ull);
  u16* pq   = (u16*)(ws + 159383552ull);
  u16* kvT  = (u16*)(ws + 226492416ull);
  float* sb = (float*)(ws + 228589568ull);
  float* kvpart = (float*)(ws + 0);            // aliases dead qb
  float* spart  = (float*)(ws + 33554432ull);
  u16* pk = (u16*)d_out;
  u16* vb = (u16*)d_out + 33554432ull;

  k_cvt_all<<<2048, 256, 0, stream>>>(query, key, Wq, Wk, Wv, qb);

  k_gemm256<1><<<512, 512, 131072, stream>>>(qb, Wqb, pq, nullptr);
  k_gemm256<2><<<512, 512, 131072, stream>>>(kb, Wkb, pk, kmask);
  k_gemm256<0><<<512, 512, 131072, stream>>>(kb, Wvb, vb, nullptr);

  k_kv2<<<512, 256, 0, stream>>>(pk, vb, kvpart, spart);
  k_red<<<64, 256, 0, stream>>>(kvpart, spart, kvT, sb);
  k_att<<<2048, 256, 0, stream>>>(pq, kvT, sb, qmask, out);
}

// Round 15
// 734.130 us; speedup vs baseline: 1.1162x; 1.0993x over previous
//
#include <hip/hip_runtime.h>
#include <stdint.h>

typedef __attribute__((ext_vector_type(8))) short    bh8;   // 8 x bf16 (4 VGPR)
typedef __attribute__((ext_vector_type(4))) float    fx4;   // MFMA acc
typedef __attribute__((ext_vector_type(4))) float    f4v;
typedef unsigned short u16;
typedef __attribute__((ext_vector_type(4))) unsigned short u16x4;

#define DEV static __device__ __forceinline__

DEV u16 f2bf(float f) {                       // RNE fp32 -> bf16
  unsigned u = __float_as_uint(f);
  u += 0x7FFFu + ((u >> 16) & 1u);
  return (u16)(u >> 16);
}
DEV float bf2f(u16 s) { return __uint_as_float(((unsigned)s) << 16); }
DEV float softplus_f(float x) { return fmaxf(x, 0.f) + log1pf(expf(-fabsf(x))); }

DEV void gload_lds16(const u16* g, u16* l) {  // 16B/lane async global->LDS
  __builtin_amdgcn_global_load_lds(
      (const __attribute__((address_space(1))) unsigned int*)g,
      (__attribute__((address_space(3))) unsigned int*)l, 16, 0, 0);
}
DEV void stage2(const u16* s, u16* d) {       // one 128-row half-tile piece
  gload_lds16(s, d);
  gload_lds16(s + 131072, d + 4096);          // +64 rows (ld = 2048)
}

// ---------------- merged fp32 -> bf16 convert (1 launch for all 5) --------
// dst = contiguous ws region qb|kb|Wqb|Wkb|Wvb (exactly 19922944 f4 groups).
__global__ __launch_bounds__(256) void k_cvt_all(
    const float* __restrict__ q, const float* __restrict__ k,
    const float* __restrict__ wq, const float* __restrict__ wk,
    const float* __restrict__ wv, u16* __restrict__ dst) {
  const int N4 = 19922944;
  int i = blockIdx.x * 256 + threadIdx.x;
  int stride = gridDim.x * 256;
  for (; i < N4; i += stride) {
    const float* src; int off;
    if (i < 8388608)        { src = q;  off = i; }
    else if (i < 16777216)  { src = k;  off = i - 8388608; }
    else if (i < 17825792)  { src = wq; off = i - 16777216; }
    else if (i < 18874368)  { src = wk; off = i - 17825792; }
    else                    { src = wv; off = i - 18874368; }
    f4v v = ((const f4v*)src)[off];
    u16x4 o;
    o.x = f2bf(v.x); o.y = f2bf(v.y); o.z = f2bf(v.z); o.w = f2bf(v.w);
    ((u16x4*)dst)[i] = o;
  }
}

// ====== 256x256 GEMM, single region per K-tile (best-known: r12, 215us) ====
// C[i,j] = sum_k A[i,k]*B[j,k]; M=16384, N=2048, K=2048 hardcoded.
// LDS (u16): buf0.A h0=0 h1=8192 buf0.B h0=16384 h1=24576; buf1 = +32768.
// Session plateau note: 634 TF/GEMM (MfmaUtil 27%). Eight schedule variants
// (r3-r14) all landed 215-247us; LDS-port and MFMA-pipe work are ~equal
// (~2300/~2480 cyc per CU per K-tile) but stack serially in every hipcc
// formulation tried. The 2.4x to m201-class interleave needs asm-level
// scheduling, not another source permutation.
// ds_read XOR-swizzle idx ^= (row&7)<<3 (conflicts=0, verified);
// staging = linear LDS dest + inverse-swizzled global source (rule #21);
// XCD-chunked block map (FETCH 286->104 MB, verified r7).

#define MM(a, b, c) __builtin_amdgcn_mfma_f32_16x16x32_bf16(a, b, c, 0, 0, 0)
#define LD(BASE, RR, KS) \
  (*(const bh8*)&lsg[(BASE) + (RR) * 64 + ((((KS) * 32) + ko8) ^ swz)])

#define DECLQ(Q)                                                          \
  fx4 acc##Q##00 = {}, acc##Q##01 = {}, acc##Q##10 = {}, acc##Q##11 = {}, \
      acc##Q##20 = {}, acc##Q##21 = {}, acc##Q##30 = {}, acc##Q##31 = {}

#define DECLFRAGS                                                         \
  bh8 a_00 = {}, a_01 = {}, a_10 = {}, a_11 = {},                         \
      a_20 = {}, a_21 = {}, a_30 = {}, a_31 = {};                         \
  bh8 b0_00 = {}, b0_01 = {}, b0_10 = {}, b0_11 = {};                     \
  bh8 b1_00 = {}, b1_01 = {}, b1_10 = {}, b1_11 = {};

#define LDA4(AB, KS)                                                     \
  a_0##KS = LD(AB, arow0,      KS); a_1##KS = LD(AB, arow0 + 16, KS);    \
  a_2##KS = LD(AB, arow0 + 32, KS); a_3##KS = LD(AB, arow0 + 48, KS);

#define LDB2(BN, BB, KS)                                                 \
  b##BN##_0##KS = LD(BB, brow0,      KS);                                \
  b##BN##_1##KS = LD(BB, brow0 + 16, KS);

#define MFMA8(Q, BN, KS)                                                 \
  acc##Q##00 = MM(a_0##KS, b##BN##_0##KS, acc##Q##00);                   \
  acc##Q##01 = MM(a_0##KS, b##BN##_1##KS, acc##Q##01);                   \
  acc##Q##10 = MM(a_1##KS, b##BN##_0##KS, acc##Q##10);                   \
  acc##Q##11 = MM(a_1##KS, b##BN##_1##KS, acc##Q##11);                   \
  acc##Q##20 = MM(a_2##KS, b##BN##_0##KS, acc##Q##20);                   \
  acc##Q##21 = MM(a_2##KS, b##BN##_1##KS, acc##Q##21);                   \
  acc##Q##30 = MM(a_3##KS, b##BN##_0##KS, acc##Q##30);                   \
  acc##Q##31 = MM(a_3##KS, b##BN##_1##KS, acc##Q##31);

// One K-tile: compute buf{ABASE,BBASE}, stage other buf {DA,DB} <- {SA,SB}.
#define KREGION(ABASE, BBASE, DA, DB, SA, SB) {                          \
  stage2(SA,            lsu + (DA));                                     \
  stage2((SA) + 262144, lsu + (DA) + 8192);                              \
  stage2(SB,            lsu + (DB));                                     \
  stage2((SB) + 262144, lsu + (DB) + 8192);                              \
  LDA4(ABASE, 0) LDA4(ABASE, 1)                                          \
  LDB2(0, BBASE, 0) LDB2(0, BBASE, 1)                                    \
  LDB2(1, (BBASE) + 8192, 0) LDB2(1, (BBASE) + 8192, 1)                  \
  __builtin_amdgcn_s_setprio(1);                                         \
  MFMA8(0, 0, 0) MFMA8(0, 0, 1) MFMA8(1, 1, 0) MFMA8(1, 1, 1)            \
  LDA4((ABASE) + 8192, 0) LDA4((ABASE) + 8192, 1)                        \
  MFMA8(2, 0, 0) MFMA8(2, 0, 1) MFMA8(3, 1, 0) MFMA8(3, 1, 1)            \
  __builtin_amdgcn_s_setprio(0);                                         \
  asm volatile("s_waitcnt vmcnt(0)");                                    \
  __builtin_amdgcn_s_barrier();                                          \
}

#define STE(AC, EL, JOFF) {                                                   \
  float v = AC.EL;                                                            \
  if (EPI >= 1) v = softplus_f(v);                                            \
  if (EPI == 2) { if (mask[gi0 + JOFF]) v = 0.f; }                            \
  C[(size_t)(gi0 + JOFF) * 2048 + gj] = f2bf(v);                              \
}
#define ST1(AC, QR, QC, MI, NI) {                                             \
  int gi0 = bm0 + (QR) * 128 + wr * 64 + (MI) * 16 + (lane >> 4) * 4;         \
  int gj  = bn0 + (QC) * 128 + wc * 32 + (NI) * 16 + l15;                     \
  STE(AC, x, 0) STE(AC, y, 1) STE(AC, z, 2) STE(AC, w, 3)                     \
}
#define EPIQ(Q, QR, QC)                                                       \
  ST1(acc##Q##00, QR, QC, 0, 0) ST1(acc##Q##01, QR, QC, 0, 1)                 \
  ST1(acc##Q##10, QR, QC, 1, 0) ST1(acc##Q##11, QR, QC, 1, 1)                 \
  ST1(acc##Q##20, QR, QC, 2, 0) ST1(acc##Q##21, QR, QC, 2, 1)                 \
  ST1(acc##Q##30, QR, QC, 3, 0) ST1(acc##Q##31, QR, QC, 3, 1)

template <int EPI>   // 0 plain, 1 softplus, 2 softplus + row-mask zero
__global__ __launch_bounds__(512, 2) void k_gemm256(
    const u16* __restrict__ A, const u16* __restrict__ B, u16* __restrict__ C,
    const int* __restrict__ mask) {
  extern __shared__ u16 lsg[];                 // 128 KiB dynamic
  int tid = threadIdx.x, lane = tid & 63, wid = tid >> 6;
  int xcd = blockIdx.x & 7, i = blockIdx.x >> 3;
  int bm0 = (xcd * 8 + (i & 7)) << 8;          // 64 M-tiles, XCD-exclusive
  int bn0 = (i >> 3) << 8;                     // 8 N-tiles
  int wr = wid >> 2, wc = wid & 3;
  int l15 = lane & 15, ko8 = (lane >> 4) * 8;
  int swz = (l15 & 7) << 3;
  int arow0 = wr * 64 + l15, brow0 = wc * 32 + l15;
  int lr = lane >> 3, cg = (lane & 7) ^ lr;    // inverse-swizzled source granule
  const u16* srcA = A + (size_t)(bm0 + wid * 8 + lr) * 2048 + cg * 8;
  const u16* srcB = B + (size_t)(bn0 + wid * 8 + lr) * 2048 + cg * 8;
  u16* lsu = lsg + wid * 512;                  // wave-uniform stage dest base

  DECLQ(0); DECLQ(1); DECLQ(2); DECLQ(3);
  DECLFRAGS

  // prologue: buf0 <- tile0 (all 4 halves); drain; barrier.
  stage2(srcA,          lsu + 0);              // b0.A h0
  stage2(srcA + 262144, lsu + 8192);           // b0.A h1
  stage2(srcB,          lsu + 16384);          // b0.B h0
  stage2(srcB + 262144, lsu + 24576);          // b0.B h1
  asm volatile("s_waitcnt vmcnt(0)");
  __builtin_amdgcn_s_barrier();

  for (int it = 0; it < 16; it++) {
    const u16* sA1 = srcA + (2 * it + 1) * 64;
    const u16* sB1 = srcB + (2 * it + 1) * 64;
    int t2 = (2 * it + 2) & 31;                // wrapped (last-iter dup, unread)
    const u16* sA2 = srcA + t2 * 64;
    const u16* sB2 = srcB + t2 * 64;
    // region 1: compute buf0, stage buf1 <- tile 2it+1
    KREGION(0,     16384, 32768, 49152, sA1, sB1)
    // region 2: compute buf1, stage buf0 <- tile 2it+2
    KREGION(32768, 49152, 0,     16384, sA2, sB2)
  }

  // epilogue: D row=(lane>>4)*4+reg, col=lane&15 (m89-verified)
  EPIQ(0, 0, 0)
  EPIQ(1, 0, 1)
  EPIQ(2, 1, 0)
  EPIQ(3, 1, 1)
}

// ------- split-K kv: part[bid][e*128+d] = sum_{k in slab} pk[k,d]*v[k,e] ----
// also computes s-partials (column sums of pk over the slab) from registers.
__global__ __launch_bounds__(256, 2) void k_kv2(const u16* __restrict__ pk,
                                                const u16* __restrict__ v,
                                                float* __restrict__ part,
                                                float* __restrict__ spart) {
  int nh = blockIdx.x >> 3, slab = blockIdx.x & 7;
  int n = nh >> 4, h = nh & 15;
  __shared__ u16 lsA[128 * 32];   // pk^T tile: [d][k]
  __shared__ u16 lsB[128 * 32];   // v^T tile:  [e][k]
  __shared__ float redS[32][128];
  int tid = threadIdx.x, lane = tid & 63, wid = tid >> 6;
  int wr = wid >> 1, wc = wid & 1;
  int kk = tid >> 3;              // 0..31 (k within 32-k slab)
  int dg = (tid & 7) * 16;        // 0..112 (16 cols per thread)
  size_t rowbase = ((size_t)(n * 4096 + slab * 512) + kk) * 2048 + h * 128 + dg;
  int r = lane & 15, ko = (lane >> 4) * 8;
  fx4 acc[4][4] = {};
  float sA[16];
#pragma unroll
  for (int i = 0; i < 16; i++) sA[i] = 0.f;
  for (int k0 = 0; k0 < 512; k0 += 32) {
    __syncthreads();
    bh8 a0 = *(const bh8*)(pk + rowbase + (size_t)k0 * 2048);
    bh8 a1 = *(const bh8*)(pk + rowbase + (size_t)k0 * 2048 + 8);
    bh8 b0 = *(const bh8*)(v + rowbase + (size_t)k0 * 2048);
    bh8 b1 = *(const bh8*)(v + rowbase + (size_t)k0 * 2048 + 8);
#pragma unroll
    for (int i = 0; i < 8; i++) {
      sA[i] += bf2f((u16)a0[i]);
      sA[8 + i] += bf2f((u16)a1[i]);
    }
#pragma unroll
    for (int i = 0; i < 8; i++) {
      lsA[(dg + i) * 32 + kk] = (u16)a0[i];
      lsA[(dg + 8 + i) * 32 + kk] = (u16)a1[i];
      lsB[(dg + i) * 32 + kk] = (u16)b0[i];
      lsB[(dg + 8 + i) * 32 + kk] = (u16)b1[i];
    }
    __syncthreads();
    bh8 af[4], bfr[4];
#pragma unroll
    for (int mi = 0; mi < 4; mi++)
      af[mi] = *(const bh8*)&lsA[(wr * 64 + mi * 16 + r) * 32 + ko];
#pragma unroll
    for (int ni = 0; ni < 4; ni++)
      bfr[ni] = *(const bh8*)&lsB[(wc * 64 + ni * 16 + r) * 32 + ko];
#pragma unroll
    for (int mi = 0; mi < 4; mi++)
#pragma unroll
      for (int ni = 0; ni < 4; ni++)
        acc[mi][ni] = __builtin_amdgcn_mfma_f32_16x16x32_bf16(af[mi], bfr[ni],
                                                              acc[mi][ni], 0, 0, 0);
  }
#pragma unroll
  for (int mi = 0; mi < 4; mi++)
#pragma unroll
    for (int ni = 0; ni < 4; ni++)
#pragma unroll
      for (int j = 0; j < 4; j++) {
        int d = wr * 64 + mi * 16 + (lane >> 4) * 4 + j;
        int e = wc * 64 + ni * 16 + (lane & 15);
        part[(size_t)blockIdx.x * 16384 + e * 128 + d] = acc[mi][ni][j];
      }
#pragma unroll
  for (int i = 0; i < 16; i++) redS[kk][dg + i] = sA[i];
  __syncthreads();
  if (tid < 128) {
    float s = 0.f;
#pragma unroll
    for (int p = 0; p < 32; p++) s += redS[p][tid];
    spart[blockIdx.x * 128 + tid] = s;
  }
}

// ------- reduce split-K partials -> kvT (bf16) and s (f32) -------
__global__ __launch_bounds__(256) void k_red(const float* __restrict__ part,
                                             const float* __restrict__ spart,
                                             u16* __restrict__ kvT,
                                             float* __restrict__ sb) {
  int nh = blockIdx.x, tid = threadIdx.x;
  for (int i = tid; i < 16384; i += 256) {
    float s = 0.f;
#pragma unroll
    for (int sl = 0; sl < 8; sl++) s += part[(size_t)(nh * 8 + sl) * 16384 + i];
    kvT[(size_t)nh * 16384 + i] = f2bf(s);
  }
  if (tid < 128) {
    float s = 0.f;
#pragma unroll
    for (int sl = 0; sl < 8; sl++) s += spart[(nh * 8 + sl) * 128 + tid];
    sb[nh * 128 + tid] = s;
  }
}

// ---------------- final: out = (pq @ kv) / (pq @ s), query-masked ----------
__global__ __launch_bounds__(256, 2) void k_att(
    const u16* __restrict__ pq, const u16* __restrict__ kvT,
    const float* __restrict__ s, const int* __restrict__ qmask,
    float* __restrict__ out) {
  int b = blockIdx.x;
  int lt = b & 31, h = (b >> 5) & 15, nb = b >> 9;
  int l0 = lt * 128;
  __shared__ u16 lsQ[128 * 128];
  __shared__ u16 lsKV[128 * 128];
  __shared__ float lsS[128];
  __shared__ float lsDen[128];
  int tid = threadIdx.x, lane = tid & 63, wid = tid >> 6;

  int row = tid >> 1, part = tid & 1;
  const u16* gq = pq + ((size_t)(nb * 4096 + l0 + row)) * 2048 + h * 128 + part * 64;
  const u16* gk = kvT + ((size_t)(nb * 16 + h) * 128 + row) * 128 + part * 64;
  int sw = (row & 7) << 3;
#pragma unroll
  for (int j = 0; j < 8; j++) {
    bh8 vq = *(const bh8*)(gq + j * 8);
    bh8 vk = *(const bh8*)(gk + j * 8);
    int ci = (part * 64 + j * 8) ^ sw;
    *(bh8*)&lsQ[row * 128 + ci] = vq;
    *(bh8*)&lsKV[row * 128 + ci] = vk;
  }
  if (tid < 128) lsS[tid] = s[(nb * 16 + h) * 128 + tid];
  __syncthreads();

  if (tid < 128) {
    int rr = tid, swr = (rr & 7) << 3;
    float dsum = 0.f;
    for (int dd = 0; dd < 128; dd++) {
      int d = (dd + rr) & 127;
      dsum += bf2f(lsQ[rr * 128 + (d ^ swr)]) * lsS[d];
    }
    lsDen[rr] = dsum;
  }
  __syncthreads();

  int wr = wid >> 1, wc = wid & 1;
  int r = lane & 15, ko = (lane >> 4) * 8;
  fx4 acc[4][4] = {};
#pragma unroll
  for (int ks = 0; ks < 4; ks++) {
    bh8 af[4], bfr[4];
#pragma unroll
    for (int mi = 0; mi < 4; mi++) {
      int rw = wr * 64 + mi * 16 + r;
      af[mi] = *(const bh8*)&lsQ[rw * 128 + ((ks * 32 + ko) ^ ((rw & 7) << 3))];
    }
#pragma unroll
    for (int ni = 0; ni < 4; ni++) {
      int rw = wc * 64 + ni * 16 + r;
      bfr[ni] = *(const bh8*)&lsKV[rw * 128 + ((ks * 32 + ko) ^ ((rw & 7) << 3))];
    }
#pragma unroll
    for (int mi = 0; mi < 4; mi++)
#pragma unroll
      for (int ni = 0; ni < 4; ni++)
        acc[mi][ni] = __builtin_amdgcn_mfma_f32_16x16x32_bf16(af[mi], bfr[ni],
                                                              acc[mi][ni], 0, 0, 0);
  }
#pragma unroll
  for (int mi = 0; mi < 4; mi++)
#pragma unroll
    for (int ni = 0; ni < 4; ni++)
#pragma unroll
      for (int j = 0; j < 4; j++) {
        int li = wr * 64 + mi * 16 + (lane >> 4) * 4 + j;
        int e = wc * 64 + ni * 16 + (lane & 15);
        int l = l0 + li;
        float v = qmask[nb * 4096 + l] ? 0.f : acc[mi][ni][j] / lsDen[li];
        out[((size_t)(nb * 4096 + l)) * 2048 + h * 128 + e] = v;
      }
}

// ---------------- launch ----------------
extern "C" void kernel_launch(void* const* d_in, const int* in_sizes, int n_in,
                              void* d_out, int out_size, void* d_ws, size_t ws_size,
                              hipStream_t stream) {
  const float* query = (const float*)d_in[0];
  const float* key   = (const float*)d_in[1];
  const float* Wq    = (const float*)d_in[2];
  const float* Wk    = (const float*)d_in[3];
  const float* Wv    = (const float*)d_in[4];
  const int* qmask   = (const int*)d_in[5];
  const int* kmask   = (const int*)d_in[6];
  float* out = (float*)d_out;
  char* ws = (char*)d_ws;

  u16* qb   = (u16*)(ws + 0);
  u16* kb   = (u16*)(ws + 67108864ull);
  u16* Wqb  = (u16*)(ws + 134217728ull);
  u16* Wkb  = (u16*)(ws + 142606336ull);
  u16* Wvb  = (u16*)(ws + 150994944ull);
  u16* pq   = (u16*)(ws + 159383552ull);
  u16* kvT  = (u16*)(ws + 226492416ull);
  float* sb = (float*)(ws + 228589568ull);
  float* kvpart = (float*)(ws + 0);            // aliases dead qb
  float* spart  = (float*)(ws + 33554432ull);
  u16* pk = (u16*)d_out;
  u16* vb = (u16*)d_out + 33554432ull;

  k_cvt_all<<<2048, 256, 0, stream>>>(query, key, Wq, Wk, Wv, qb);

  k_gemm256<1><<<512, 512, 131072, stream>>>(qb, Wqb, pq, nullptr);
  k_gemm256<2><<<512, 512, 131072, stream>>>(kb, Wkb, pk, kmask);
  k_gemm256<0><<<512, 512, 131072, stream>>>(kb, Wvb, vb, nullptr);

  k_kv2<<<512, 256, 0, stream>>>(pk, vb, kvpart, spart);
  k_red<<<64, 256, 0, stream>>>(kvpart, spart, kvT, sb);
  k_att<<<2048, 256, 0, stream>>>(pq, kvT, sb, qmask, out);
}